// Round 1
// baseline (327.834 us; speedup 1.0000x reference)
//
#include <hip/hip_runtime.h>

#define N_COLS 256
#define M_ROWS 65536
#define DIM    512
#define NT     64      // cols per block
#define MT     256     // rows (j) per block
#define JT     64      // j sub-tile
#define DC     128     // d chunk
#define TOPK   10
#define NBN    (N_COLS / NT)   // 4
#define NBM    (M_ROWS / MT)   // 256
#define NEG_INIT (-3.0e38f)
#define PART_STRIDE 12         // 10 topk + pos_sum + pos_cnt

// K1: per (n-tile, m-block): sim tile 64x256, fused pos stats + per-col top-10 partials.
__global__ __launch_bounds__(256, 2)
void k1_partials(const float* __restrict__ colm, const int* __restrict__ clab_g,
                 const float* __restrict__ rowm, const int* __restrict__ rlab_g,
                 float* __restrict__ part) {
    __shared__ float smem[DC * NT + DC * JT];   // 64 KB; merge buffer aliases it later
    float* cS = smem;             // [dd][c]  transposed, 32 KB
    float* rS = smem + DC * NT;   // [dd][j]  transposed, 32 KB

    const int t  = threadIdx.x;
    const int bn = blockIdx.x & (NBN - 1);
    const int bm = blockIdx.x >> 2;            // log2(NBN) = 2
    const int n0  = bn * NT;
    const int jm0 = bm * MT;
    const int tc = t & 15;      // col group (4 cols)
    const int tj = t >> 4;      // j group   (4 js)
    const int sl = t & 63;      // staging lane
    const int sq = t >> 6;      // staging quarter (= wave id)

    int clab[4];
#pragma unroll
    for (int ci = 0; ci < 4; ++ci) clab[ci] = clab_g[n0 + 4 * tc + ci];

    float tk[4][TOPK];
#pragma unroll
    for (int ci = 0; ci < 4; ++ci)
#pragma unroll
        for (int r = 0; r < TOPK; ++r) tk[ci][r] = NEG_INIT;
    float psum[4] = {0.f, 0.f, 0.f, 0.f};
    int   pcnt[4] = {0, 0, 0, 0};

    for (int jt = 0; jt < MT / JT; ++jt) {
        const int j0 = jm0 + jt * JT;
        float acc[4][4] = {};
        for (int dc = 0; dc < DIM / DC; ++dc) {
            __syncthreads();   // previous compute (or nothing) done before overwrite
            // stage cols transposed: cS[dd][c] = colm[n0+c][dc*DC+dd]
            {
                const float4* g = reinterpret_cast<const float4*>(
                    colm + (size_t)(n0 + sl) * DIM + dc * DC + sq * 32);
#pragma unroll
                for (int k = 0; k < 8; ++k) {
                    float4 v = g[k];
                    int dd = sq * 32 + k * 4;
                    cS[(dd + 0) * NT + sl] = v.x;
                    cS[(dd + 1) * NT + sl] = v.y;
                    cS[(dd + 2) * NT + sl] = v.z;
                    cS[(dd + 3) * NT + sl] = v.w;
                }
            }
            // stage rows transposed: rS[dd][j] = rowm[j0+j][dc*DC+dd]
            {
                const float4* g = reinterpret_cast<const float4*>(
                    rowm + (size_t)(j0 + sl) * DIM + dc * DC + sq * 32);
#pragma unroll
                for (int k = 0; k < 8; ++k) {
                    float4 v = g[k];
                    int dd = sq * 32 + k * 4;
                    rS[(dd + 0) * JT + sl] = v.x;
                    rS[(dd + 1) * JT + sl] = v.y;
                    rS[(dd + 2) * JT + sl] = v.z;
                    rS[(dd + 3) * JT + sl] = v.w;
                }
            }
            __syncthreads();
#pragma unroll 8
            for (int dd = 0; dd < DC; ++dd) {
                float4 a = *reinterpret_cast<const float4*>(&cS[dd * NT + 4 * tc]);
                float4 b = *reinterpret_cast<const float4*>(&rS[dd * JT + 4 * tj]);
                acc[0][0] += a.x * b.x; acc[0][1] += a.x * b.y;
                acc[0][2] += a.x * b.z; acc[0][3] += a.x * b.w;
                acc[1][0] += a.y * b.x; acc[1][1] += a.y * b.y;
                acc[1][2] += a.y * b.z; acc[1][3] += a.y * b.w;
                acc[2][0] += a.z * b.x; acc[2][1] += a.z * b.y;
                acc[2][2] += a.z * b.z; acc[2][3] += a.z * b.w;
                acc[3][0] += a.w * b.x; acc[3][1] += a.w * b.y;
                acc[3][2] += a.w * b.z; acc[3][3] += a.w * b.w;
            }
        }
        // fused epilogue for this j-tile (registers only)
        int tlab[4];
#pragma unroll
        for (int ji = 0; ji < 4; ++ji) tlab[ji] = rlab_g[j0 + 4 * tj + ji];
#pragma unroll
        for (int ci = 0; ci < 4; ++ci) {
#pragma unroll
            for (int ji = 0; ji < 4; ++ji) {
                float s = acc[ci][ji];
                bool same = (clab[ci] == tlab[ji]);
                if (same) {
                    if (s < 0.99999f) { psum[ci] += 1.0f - s; pcnt[ci] += 1; }
                } else if (s > tk[ci][TOPK - 1]) {
                    float v = s;
#pragma unroll
                    for (int r = 0; r < TOPK; ++r) {   // branchless sorted insert (desc)
                        float old = tk[ci][r];
                        bool gt = v > old;
                        tk[ci][r] = gt ? v : old;
                        v = gt ? old : v;
                    }
                }
            }
        }
    }

    // block-level merge across the 16 j-groups, per col
    __syncthreads();   // all compute done; safe to alias smem
#pragma unroll
    for (int ci = 0; ci < 4; ++ci) {
        float* mb = &smem[((4 * tc + ci) * 16 + tj) * PART_STRIDE];
#pragma unroll
        for (int r = 0; r < TOPK; ++r) mb[r] = tk[ci][r];
        mb[10] = psum[ci];
        mb[11] = (float)pcnt[ci];
    }
    __syncthreads();
    if (t < NT) {
        float best[TOPK];
#pragma unroll
        for (int r = 0; r < TOPK; ++r) best[r] = NEG_INIT;
        float ps = 0.f, pc = 0.f;
        for (int u = 0; u < 16; ++u) {
            const float* mb = &smem[(t * 16 + u) * PART_STRIDE];
            ps += mb[10];
            pc += mb[11];
#pragma unroll
            for (int r = 0; r < TOPK; ++r) {
                float v = mb[r];
                if (v > best[TOPK - 1]) {
                    float w = v;
#pragma unroll
                    for (int q = 0; q < TOPK; ++q) {
                        float old = best[q];
                        bool gt = w > old;
                        best[q] = gt ? w : old;
                        w = gt ? old : w;
                    }
                }
            }
        }
        float* wp = part + ((size_t)(n0 + t) * NBM + bm) * PART_STRIDE;
#pragma unroll
        for (int r = 0; r < TOPK; ++r) wp[r] = best[r];
        wp[10] = ps;
        wp[11] = pc;
    }
}

// K2: one block per col; merge 256 partial sorted top-10 lists + pos stats -> per-col loss.
__global__ __launch_bounds__(256)
void k2_merge(const float* __restrict__ part, float* __restrict__ colloss) {
    __shared__ float vs[256 * TOPK];
    __shared__ float rv[256];
    __shared__ int   ri[256];
    const int c = blockIdx.x, t = threadIdx.x;
    const float* wp = part + ((size_t)c * NBM + t) * PART_STRIDE;
    float ps = wp[10], pc = wp[11];
#pragma unroll
    for (int r = 0; r < TOPK; ++r) vs[t * TOPK + r] = wp[r];

    rv[t] = ps; __syncthreads();
    for (int s = 128; s > 0; s >>= 1) { if (t < s) rv[t] += rv[t + s]; __syncthreads(); }
    float ps_tot = rv[0]; __syncthreads();
    rv[t] = pc; __syncthreads();
    for (int s = 128; s > 0; s >>= 1) { if (t < s) rv[t] += rv[t + s]; __syncthreads(); }
    float pc_tot = rv[0]; __syncthreads();

    // global top-10 via pointer-walk over 256 sorted lists (multiset-correct)
    int p = 0;
    float cand = vs[t * TOPK];
    float negsum = 0.f;
    for (int r = 0; r < TOPK; ++r) {
        rv[t] = cand; ri[t] = t; __syncthreads();
        for (int s = 128; s > 0; s >>= 1) {
            if (t < s && rv[t + s] > rv[t]) { rv[t] = rv[t + s]; ri[t] = ri[t + s]; }
            __syncthreads();
        }
        negsum += rv[0];
        if (t == ri[0]) { ++p; cand = (p < TOPK) ? vs[t * TOPK + p] : NEG_INIT; }
        __syncthreads();
    }

    if (t == 0) {
        float pos_loss = (pc_tot > 0.5f) ? 6.0f * ps_tot / pc_tot : 0.0f;
        colloss[c] = pos_loss + 15.0f * (negsum / (float)TOPK);
    }
}

// K3: final scalar reduce.
__global__ __launch_bounds__(256)
void k3_final(const float* __restrict__ colloss, float* __restrict__ out) {
    __shared__ float rv[256];
    const int t = threadIdx.x;
    rv[t] = colloss[t];
    __syncthreads();
    for (int s = 128; s > 0; s >>= 1) { if (t < s) rv[t] += rv[t + s]; __syncthreads(); }
    if (t == 0) out[0] = rv[0] / (float)N_COLS;
}

extern "C" void kernel_launch(void* const* d_in, const int* in_sizes, int n_in,
                              void* d_out, int out_size, void* d_ws, size_t ws_size,
                              hipStream_t stream) {
    const float* colm = (const float*)d_in[0];   // [256, 512] f32
    const int*   clab = (const int*)d_in[1];     // [256] i32
    const float* rowm = (const float*)d_in[2];   // [65536, 512] f32
    const int*   rlab = (const int*)d_in[3];     // [65536] i32
    float* part    = (float*)d_ws;                                   // 256*256*12 floats = 3 MB
    float* colloss = part + (size_t)N_COLS * NBM * PART_STRIDE;      // 256 floats
    float* out     = (float*)d_out;

    hipLaunchKernelGGL(k1_partials, dim3(NBN * NBM), dim3(256), 0, stream,
                       colm, clab, rowm, rlab, part);
    hipLaunchKernelGGL(k2_merge, dim3(N_COLS), dim3(256), 0, stream, part, colloss);
    hipLaunchKernelGGL(k3_final, dim3(1), dim3(256), 0, stream, colloss, out);
}

// Round 2
// 81.415 us; speedup vs baseline: 4.0267x; 4.0267x over previous
//
#include <hip/hip_runtime.h>

#define N_COLS 256
#define M_ROWS 65536
#define DIM    512
#define MT     256
#define NBM    (M_ROWS / MT)   // 256
#define TOPK   10
#define NEG_INIT (-3.0e38f)
#define PART_STRIDE 12
#define BK     64

typedef float f32x4  __attribute__((ext_vector_type(4)));
typedef short bf16x8 __attribute__((ext_vector_type(8)));

__device__ __forceinline__ short f2bf(float x) {
    union { float f; unsigned u; } v; v.f = x;
    unsigned r = v.u + 0x7fffu + ((v.u >> 16) & 1u);   // RNE
    return (short)(r >> 16);
}

__device__ __forceinline__ bf16x8 cvt8(float4 a, float4 b) {
    bf16x8 r;
    r[0] = f2bf(a.x); r[1] = f2bf(a.y); r[2] = f2bf(a.z); r[3] = f2bf(a.w);
    r[4] = f2bf(b.x); r[5] = f2bf(b.y); r[6] = f2bf(b.z); r[7] = f2bf(b.w);
    return r;
}

// K1: block bm computes sim[0:256][bm*256:(bm+1)*256] via bf16 MFMA with fused
// top-10 + positive-stats epilogue; writes 12-float partial per (n, bm).
__global__ __launch_bounds__(512, 2)
void k1_mfma(const float* __restrict__ colm, const int* __restrict__ clab_g,
             const float* __restrict__ rowm, const int* __restrict__ rlab_g,
             float* __restrict__ part) {
    __shared__ char smem[131072];   // 2x(A 32KB) + 2x(B 32KB); epilogue aliases all
    __shared__ int  rlabS[256];

    const int t   = threadIdx.x;
    const int bm  = blockIdx.x;
    const int jm0 = bm * MT;
    const int w   = t >> 6;
    const int l   = t & 63;
    const int lr  = l & 15, lq = l >> 4;
    const int wn  = (w >> 2) * 128;   // wave n-offset (2 rows of waves)
    const int wm  = (w & 3) * 64;     // wave m-offset (4 cols of waves)

    if (t < 256) rlabS[t] = rlab_g[jm0 + t];
    const int clab_n = clab_g[t & 255];

    // staging lane constants: thread stages 4 rows x 16 bf16 per matrix per stage
    const int srow = t >> 3;                         // 0..63 (+ i*64)
    const int sg   = t & 7;                          // 16B-granule within 128B row
    const int swzW = ((sg ^ (srow & 7)) << 4);       // swizzled write byte-offset

    f32x4 acc[8][4];
#pragma unroll
    for (int ni = 0; ni < 8; ++ni)
#pragma unroll
        for (int mj = 0; mj < 4; ++mj) acc[ni][mj] = (f32x4){0.f, 0.f, 0.f, 0.f};

    float4 LA[8], LB[8];

#define LOAD_STAGE(k0)                                                          \
    do {                                                                        \
        _Pragma("unroll") for (int i = 0; i < 4; ++i) {                         \
            size_t ra = (size_t)(i * 64 + srow) * DIM + (k0) + sg * 8;          \
            LA[2*i]   = *reinterpret_cast<const float4*>(colm + ra);            \
            LA[2*i+1] = *reinterpret_cast<const float4*>(colm + ra + 4);        \
            size_t rb = (size_t)(jm0 + i * 64 + srow) * DIM + (k0) + sg * 8;    \
            LB[2*i]   = *reinterpret_cast<const float4*>(rowm + rb);            \
            LB[2*i+1] = *reinterpret_cast<const float4*>(rowm + rb + 4);        \
        }                                                                       \
    } while (0)

#define WRITE_STAGE(buf)                                                        \
    do {                                                                        \
        char* aB = smem + (buf) * 32768;                                        \
        char* bB = smem + 65536 + (buf) * 32768;                                \
        _Pragma("unroll") for (int i = 0; i < 4; ++i) {                         \
            int off = (i * 64 + srow) * 128 + swzW;                             \
            *reinterpret_cast<bf16x8*>(aB + off) = cvt8(LA[2*i], LA[2*i+1]);    \
            *reinterpret_cast<bf16x8*>(bB + off) = cvt8(LB[2*i], LB[2*i+1]);    \
        }                                                                       \
    } while (0)

#define KSTEP(buf, kk)                                                          \
    do {                                                                        \
        const char* aB = smem + (buf) * 32768;                                  \
        const char* bB = smem + 65536 + (buf) * 32768;                          \
        bf16x8 aF[8], bF[4];                                                    \
        _Pragma("unroll") for (int ni = 0; ni < 8; ++ni) {                      \
            int row = wn + ni * 16 + lr;                                        \
            int off = row * 128 + (((((kk) >> 3) + lq) ^ (lr & 7)) << 4);       \
            aF[ni] = *reinterpret_cast<const bf16x8*>(aB + off);                \
        }                                                                       \
        _Pragma("unroll") for (int mj = 0; mj < 4; ++mj) {                      \
            int row = wm + mj * 16 + lr;                                        \
            int off = row * 128 + (((((kk) >> 3) + lq) ^ (lr & 7)) << 4);       \
            bF[mj] = *reinterpret_cast<const bf16x8*>(bB + off);                \
        }                                                                       \
        _Pragma("unroll") for (int ni = 0; ni < 8; ++ni)                        \
            _Pragma("unroll") for (int mj = 0; mj < 4; ++mj)                    \
                acc[ni][mj] = __builtin_amdgcn_mfma_f32_16x16x32_bf16(          \
                    aF[ni], bF[mj], acc[ni][mj], 0, 0, 0);                      \
    } while (0)

    // prologue
    LOAD_STAGE(0);
    WRITE_STAGE(0);
    __syncthreads();

#pragma unroll 2
    for (int s = 0; s < DIM / BK; ++s) {
        if (s < DIM / BK - 1) LOAD_STAGE((s + 1) * BK);   // prefetch next stage
        KSTEP(s & 1, 0);
        KSTEP(s & 1, 32);
        if (s < DIM / BK - 1) WRITE_STAGE((s + 1) & 1);
        __syncthreads();
    }

    // ---- fused epilogue: sim -> per-thread top-10 + pos stats ----
    float tk[TOPK];
#pragma unroll
    for (int r = 0; r < TOPK; ++r) tk[r] = NEG_INIT;
    float psum = 0.f; int pcnt = 0;

    float* simF = reinterpret_cast<float*>(smem);
    const int myChunk = (w & 3) >> 1;          // which 128-m half this wave's acc is in
    const int n = t & 255, h = t >> 8;

    for (int c = 0; c < 2; ++c) {
        if (myChunk == c) {
#pragma unroll
            for (int ni = 0; ni < 8; ++ni)
#pragma unroll
                for (int mj = 0; mj < 4; ++mj) {
                    int mloc = (wm & 127) + mj * 16 + lr;        // 0..127
                    int n0   = wn + ni * 16 + lq * 4;            // mult of 4
                    int off  = mloc * 256 + (((n0 >> 2) ^ (mloc & 7)) << 2);
                    float4 v;
                    v.x = acc[ni][mj][0]; v.y = acc[ni][mj][1];
                    v.z = acc[ni][mj][2]; v.w = acc[ni][mj][3];
                    *reinterpret_cast<float4*>(simF + off) = v;
                }
        }
        __syncthreads();
#pragma unroll 8
        for (int mm = 0; mm < 64; ++mm) {
            int mloc = h * 64 + mm;
            float s  = simF[mloc * 256 + ((((n >> 2) ^ (mloc & 7)) << 2) | (n & 3))];
            int lab  = rlabS[c * 128 + mloc];
            if (lab == clab_n) {
                if (s < 0.99999f) { psum += 1.0f - s; pcnt += 1; }
            } else if (s > tk[TOPK - 1]) {
                float v = s;
#pragma unroll
                for (int r = 0; r < TOPK; ++r) {
                    float old = tk[r]; bool gt = v > old;
                    tk[r] = gt ? v : old; v = gt ? old : v;
                }
            }
        }
        __syncthreads();
    }

    // merge the two m-halves per n, write one partial per (n, bm)
    {
        float* mb = simF + t * PART_STRIDE;
#pragma unroll
        for (int r = 0; r < TOPK; ++r) mb[r] = tk[r];
        mb[10] = psum; mb[11] = (float)pcnt;
    }
    __syncthreads();
    if (t < 256) {
        const float* La = simF + t * PART_STRIDE;
        const float* Lb = simF + (t + 256) * PART_STRIDE;
        float best[TOPK];
        int ia = 0, ib = 0;
#pragma unroll
        for (int r = 0; r < TOPK; ++r) {
            float va = La[ia], vb = Lb[ib];
            bool ta = va >= vb;
            best[r] = ta ? va : vb;
            ia += ta; ib += !ta;
        }
        float* wp = part + ((size_t)t * NBM + bm) * PART_STRIDE;
#pragma unroll
        for (int r = 0; r < TOPK; ++r) wp[r] = best[r];
        wp[10] = La[10] + Lb[10];
        wp[11] = La[11] + Lb[11];
    }
#undef LOAD_STAGE
#undef WRITE_STAGE
#undef KSTEP
}

// K2: one block per col; merge 256 partial sorted top-10 lists + pos stats -> per-col loss.
__global__ __launch_bounds__(256)
void k2_merge(const float* __restrict__ part, float* __restrict__ colloss) {
    __shared__ float vs[256 * TOPK];
    __shared__ float rv[256];
    __shared__ int   ri[256];
    const int c = blockIdx.x, t = threadIdx.x;
    const float* wp = part + ((size_t)c * NBM + t) * PART_STRIDE;
    float ps = wp[10], pc = wp[11];
#pragma unroll
    for (int r = 0; r < TOPK; ++r) vs[t * TOPK + r] = wp[r];

    rv[t] = ps; __syncthreads();
    for (int s = 128; s > 0; s >>= 1) { if (t < s) rv[t] += rv[t + s]; __syncthreads(); }
    float ps_tot = rv[0]; __syncthreads();
    rv[t] = pc; __syncthreads();
    for (int s = 128; s > 0; s >>= 1) { if (t < s) rv[t] += rv[t + s]; __syncthreads(); }
    float pc_tot = rv[0]; __syncthreads();

    // global top-10 via pointer-walk over 256 sorted lists (multiset-correct)
    int p = 0;
    float cand = vs[t * TOPK];
    float negsum = 0.f;
    for (int r = 0; r < TOPK; ++r) {
        rv[t] = cand; ri[t] = t; __syncthreads();
        for (int s = 128; s > 0; s >>= 1) {
            if (t < s && rv[t + s] > rv[t]) { rv[t] = rv[t + s]; ri[t] = ri[t + s]; }
            __syncthreads();
        }
        negsum += rv[0];
        if (t == ri[0]) { ++p; cand = (p < TOPK) ? vs[t * TOPK + p] : NEG_INIT; }
        __syncthreads();
    }

    if (t == 0) {
        float pos_loss = (pc_tot > 0.5f) ? 6.0f * ps_tot / pc_tot : 0.0f;
        colloss[c] = pos_loss + 15.0f * (negsum / (float)TOPK);
    }
}

// K3: final scalar reduce.
__global__ __launch_bounds__(256)
void k3_final(const float* __restrict__ colloss, float* __restrict__ out) {
    __shared__ float rv[256];
    const int t = threadIdx.x;
    rv[t] = colloss[t];
    __syncthreads();
    for (int s = 128; s > 0; s >>= 1) { if (t < s) rv[t] += rv[t + s]; __syncthreads(); }
    if (t == 0) out[0] = rv[0] / (float)N_COLS;
}

extern "C" void kernel_launch(void* const* d_in, const int* in_sizes, int n_in,
                              void* d_out, int out_size, void* d_ws, size_t ws_size,
                              hipStream_t stream) {
    const float* colm = (const float*)d_in[0];   // [256, 512] f32
    const int*   clab = (const int*)d_in[1];     // [256] i32
    const float* rowm = (const float*)d_in[2];   // [65536, 512] f32
    const int*   rlab = (const int*)d_in[3];     // [65536] i32
    float* part    = (float*)d_ws;                                   // 256*256*12 floats = 3 MB
    float* colloss = part + (size_t)N_COLS * NBM * PART_STRIDE;      // 256 floats
    float* out     = (float*)d_out;

    hipLaunchKernelGGL(k1_mfma, dim3(NBM), dim3(512), 0, stream,
                       colm, clab, rowm, rlab, part);
    hipLaunchKernelGGL(k2_merge, dim3(N_COLS), dim3(256), 0, stream, part, colloss);
    hipLaunchKernelGGL(k3_final, dim3(1), dim3(256), 0, stream, colloss, out);
}